// Round 3
// baseline (585.748 us; speedup 1.0000x reference)
//
#include <hip/hip_runtime.h>

#define NN   100000   // nodes
#define EE   1600000  // edges
#define DD   64       // feature dim
#define DOUT 16       // output dim
#define CAP  64       // max in-degree slots (Poisson(16): P(deg>64) ~ 1e-18)
#define NPW  8        // nodes per wave in fused kernels

// --- binning pipeline params ---
#define EPB  8192                      // edges per block in hist/scatter
#define NBL  ((EE + EPB - 1) / EPB)    // 196 blocks
#define BSH  9                         // bucket = dst >> 9 (512 nodes/bucket)
#define NB   196                       // ceil(100000 / 512)

// ---------------------------------------------------------------------------
// K1: per-block histogram over NB dst-buckets. hist[bucket*NBL + block].
// ---------------------------------------------------------------------------
__global__ __launch_bounds__(256) void k_hist(const int* __restrict__ ei,
                                              int* __restrict__ hist) {
    __shared__ int h[NB];
    for (int i = threadIdx.x; i < NB; i += 256) h[i] = 0;
    __syncthreads();
    int e0 = blockIdx.x * EPB;
    int e1 = min(e0 + EPB, EE);
    for (int e = e0 + (int)threadIdx.x; e < e1; e += 256) {
        int d = ei[EE + e];
        atomicAdd(&h[d >> BSH], 1);
    }
    __syncthreads();
    for (int i = threadIdx.x; i < NB; i += 256)
        hist[i * NBL + blockIdx.x] = h[i];
}

// ---------------------------------------------------------------------------
// K2: single-block exclusive scan of the NB*NBL histogram matrix (in place).
// Gives every (bucket, block) a private contiguous output range.
// ---------------------------------------------------------------------------
__global__ __launch_bounds__(256) void k_scan(int* __restrict__ hist) {
    const int TOT = NB * NBL;
    const int CH  = (TOT + 255) / 256;
    __shared__ int part[256];
    int t  = threadIdx.x;
    int lo = t * CH, hi = min(lo + CH, TOT);
    int s = 0;
    for (int i = lo; i < hi; ++i) s += hist[i];
    part[t] = s;
    __syncthreads();
    for (int off = 1; off < 256; off <<= 1) {   // Hillis-Steele inclusive
        int v = (t >= off) ? part[t - off] : 0;
        __syncthreads();
        part[t] += v;
        __syncthreads();
    }
    int base = (t == 0) ? 0 : part[t - 1];
    for (int i = lo; i < hi; ++i) {   // serial exclusive rescan of own chunk
        int v = hist[i];
        hist[i] = base;
        base += v;
    }
}

// ---------------------------------------------------------------------------
// K3: scatter edges into bucket-grouped arrays. Each block appends into its
// private ranges (from K2) -> sequential full-line writes, no XCD bouncing.
// ---------------------------------------------------------------------------
__global__ __launch_bounds__(256) void k_scatter(const int* __restrict__ ei,
                                                 const int* __restrict__ hist,
                                                 int* __restrict__ bsrc,
                                                 int* __restrict__ bdst) {
    __shared__ int cur[NB];
    for (int i = threadIdx.x; i < NB; i += 256)
        cur[i] = hist[i * NBL + blockIdx.x];
    __syncthreads();
    int e0 = blockIdx.x * EPB;
    int e1 = min(e0 + EPB, EE);
    for (int e = e0 + (int)threadIdx.x; e < e1; e += 256) {
        int s = ei[e], d = ei[EE + e];
        int p = atomicAdd(&cur[d >> BSH], 1);
        bsrc[p] = s;
        bdst[p] = d;
    }
}

// ---------------------------------------------------------------------------
// K4: build padded CSR bucket-by-bucket. One block per bucket: its 128 KB CSR
// window is written in one short window by one XCD -> L2-resident, writeback
// ~= touched lines (~10 MB total vs 96 MB for the naive scatter).
// ---------------------------------------------------------------------------
__global__ __launch_bounds__(256) void k_csr(const int* __restrict__ bsrc,
                                             const int* __restrict__ bdst,
                                             const int* __restrict__ hist,
                                             int* __restrict__ cnt,
                                             int* __restrict__ csr) {
    int b  = blockIdx.x;
    int lo = hist[b * NBL];
    int hi = (b == NB - 1) ? EE : hist[(b + 1) * NBL];
    for (int e = lo + (int)threadIdx.x; e < hi; e += 256) {
        int s = bsrc[e], d = bdst[e];
        int pos = atomicAdd(&cnt[d], 1);
        if (pos < CAP) csr[(size_t)d * CAP + pos] = s;
    }
}

__global__ __launch_bounds__(256) void k_dinv(const int* __restrict__ cnt,
                                              float* __restrict__ dinv) {
    int n = blockIdx.x * 256 + threadIdx.x;
    if (n < NN) dinv[n] = rsqrtf((float)cnt[n] + 1.0f);
}

// ---------------------------------------------------------------------------
// hp[n][j] = (sum_k in[n][k] * W[k][j]) * dinv[n]   (layer-1 pre-transform)
// ---------------------------------------------------------------------------
template <int ROWS>
__global__ __launch_bounds__(256) void k_gemm_scale(const float* __restrict__ in,
                                                    const float* __restrict__ W,
                                                    const float* __restrict__ dinv,
                                                    float* __restrict__ out) {
    const int lane = threadIdx.x & 63;
    const int wv   = threadIdx.x >> 6;
    float Wreg[DD];
#pragma unroll
    for (int k = 0; k < DD; ++k) Wreg[k] = W[k * DD + lane];  // coalesced

    int base = (blockIdx.x * 4 + wv) * ROWS;
    for (int r = 0; r < ROWS; ++r) {
        int n = base + r;
        if (n >= NN) return;
        const float4* row = (const float4*)(in + (size_t)n * DD);
        float acc = 0.f;
#pragma unroll
        for (int kk = 0; kk < DD / 4; ++kk) {
            float4 q = row[kk];  // uniform address -> broadcast
            acc = fmaf(q.x, Wreg[4 * kk + 0], acc);
            acc = fmaf(q.y, Wreg[4 * kk + 1], acc);
            acc = fmaf(q.z, Wreg[4 * kk + 2], acc);
            acc = fmaf(q.w, Wreg[4 * kk + 3], acc);
        }
        out[(size_t)n * DD + lane] = acc * dinv[n];
    }
}

// ---------------------------------------------------------------------------
// Fused layer: t = relu(dinv[n]*(hp[n] + sum_src hp[src]) + bias)
//              hpn[n] = (t @ Wn) * dinv[n]
// ---------------------------------------------------------------------------
__global__ __launch_bounds__(256) void k_fused(const float* __restrict__ hp,
                                               const int* __restrict__ csr,
                                               const int* __restrict__ cnt,
                                               const float* __restrict__ dinv,
                                               const float* __restrict__ bias,
                                               const float* __restrict__ Wn,
                                               float* __restrict__ hpn) {
    __shared__ float tbuf[4][DD];
    const int lane = threadIdx.x & 63;
    const int wv   = threadIdx.x >> 6;

    float Wreg[DD];
#pragma unroll
    for (int k = 0; k < DD; ++k) Wreg[k] = Wn[k * DD + lane];
    const float bv = bias[lane];

    int base = (blockIdx.x * 4 + wv) * NPW;
    for (int r = 0; r < NPW; ++r) {
        int n = base + r;
        if (n >= NN) return;
        int my = csr[(size_t)n * CAP + lane];  // coalesced index row
        int c  = cnt[n];
        if (c > CAP) c = CAP;
        float dv = dinv[n];

        float acc = hp[(size_t)n * DD + lane];  // self-loop term
        int i = 0;
        for (; i + 8 <= c; i += 8) {  // 8 outstanding gathers
            int s0 = __shfl(my, i + 0), s1 = __shfl(my, i + 1);
            int s2 = __shfl(my, i + 2), s3 = __shfl(my, i + 3);
            int s4 = __shfl(my, i + 4), s5 = __shfl(my, i + 5);
            int s6 = __shfl(my, i + 6), s7 = __shfl(my, i + 7);
            float a0 = hp[(size_t)s0 * DD + lane];
            float a1 = hp[(size_t)s1 * DD + lane];
            float a2 = hp[(size_t)s2 * DD + lane];
            float a3 = hp[(size_t)s3 * DD + lane];
            float a4 = hp[(size_t)s4 * DD + lane];
            float a5 = hp[(size_t)s5 * DD + lane];
            float a6 = hp[(size_t)s6 * DD + lane];
            float a7 = hp[(size_t)s7 * DD + lane];
            acc += ((a0 + a1) + (a2 + a3)) + ((a4 + a5) + (a6 + a7));
        }
        for (; i < c; ++i) {
            int s = __shfl(my, i);
            acc += hp[(size_t)s * DD + lane];
        }
        float t = fmaxf(fmaf(dv, acc, bv), 0.f);

        // t @ Wn via LDS round-trip (wave-private slot)
        tbuf[wv][lane] = t;
        const float4* tb = (const float4*)tbuf[wv];
        float o = 0.f;
#pragma unroll
        for (int kk = 0; kk < DD / 4; ++kk) {
            float4 q = tb[kk];  // wave-uniform -> LDS broadcast
            o = fmaf(q.x, Wreg[4 * kk + 0], o);
            o = fmaf(q.y, Wreg[4 * kk + 1], o);
            o = fmaf(q.z, Wreg[4 * kk + 2], o);
            o = fmaf(q.w, Wreg[4 * kk + 3], o);
        }
        hpn[(size_t)n * DD + lane] = o * dv;
    }
}

// ---------------------------------------------------------------------------
// Final fused layer: t3 = relu(dinv*(agg)+b3); u = relu(t3@Wf1+bf1);
//                    out = u@Wf2 + bf2.
// ---------------------------------------------------------------------------
__global__ __launch_bounds__(256) void k_fused_ffn(const float* __restrict__ hp,
                                                   const int* __restrict__ csr,
                                                   const int* __restrict__ cnt,
                                                   const float* __restrict__ dinv,
                                                   const float* __restrict__ b3,
                                                   const float* __restrict__ Wf1,
                                                   const float* __restrict__ bf1,
                                                   const float* __restrict__ Wf2,
                                                   const float* __restrict__ bf2,
                                                   float* __restrict__ out) {
    __shared__ float tbuf[4][DD];
    __shared__ float ubuf[4][DD];
    const int lane = threadIdx.x & 63;
    const int wv   = threadIdx.x >> 6;
    const int q    = lane >> 4;   // quarter 0..3
    const int jj   = lane & 15;   // output feature

    float W1reg[DD];
#pragma unroll
    for (int k = 0; k < DD; ++k) W1reg[k] = Wf1[k * DD + lane];
    float W2reg[16];
#pragma unroll
    for (int kk = 0; kk < 16; ++kk) W2reg[kk] = Wf2[(q * 16 + kk) * DOUT + jj];
    const float b3v = b3[lane];
    const float b1v = bf1[lane];
    const float b2v = bf2[jj];

    int base = (blockIdx.x * 4 + wv) * NPW;
    for (int r = 0; r < NPW; ++r) {
        int n = base + r;
        if (n >= NN) return;
        int my = csr[(size_t)n * CAP + lane];
        int c  = cnt[n];
        if (c > CAP) c = CAP;
        float dv = dinv[n];

        float acc = hp[(size_t)n * DD + lane];
        int i = 0;
        for (; i + 8 <= c; i += 8) {
            int s0 = __shfl(my, i + 0), s1 = __shfl(my, i + 1);
            int s2 = __shfl(my, i + 2), s3 = __shfl(my, i + 3);
            int s4 = __shfl(my, i + 4), s5 = __shfl(my, i + 5);
            int s6 = __shfl(my, i + 6), s7 = __shfl(my, i + 7);
            float a0 = hp[(size_t)s0 * DD + lane];
            float a1 = hp[(size_t)s1 * DD + lane];
            float a2 = hp[(size_t)s2 * DD + lane];
            float a3 = hp[(size_t)s3 * DD + lane];
            float a4 = hp[(size_t)s4 * DD + lane];
            float a5 = hp[(size_t)s5 * DD + lane];
            float a6 = hp[(size_t)s6 * DD + lane];
            float a7 = hp[(size_t)s7 * DD + lane];
            acc += ((a0 + a1) + (a2 + a3)) + ((a4 + a5) + (a6 + a7));
        }
        for (; i < c; ++i) {
            int s = __shfl(my, i);
            acc += hp[(size_t)s * DD + lane];
        }
        float t = fmaxf(fmaf(dv, acc, b3v), 0.f);

        // u = relu(t @ Wf1 + bf1)
        tbuf[wv][lane] = t;
        const float4* tb = (const float4*)tbuf[wv];
        float u = b1v;
#pragma unroll
        for (int kk = 0; kk < DD / 4; ++kk) {
            float4 qd = tb[kk];
            u = fmaf(qd.x, W1reg[4 * kk + 0], u);
            u = fmaf(qd.y, W1reg[4 * kk + 1], u);
            u = fmaf(qd.z, W1reg[4 * kk + 2], u);
            u = fmaf(qd.w, W1reg[4 * kk + 3], u);
        }
        u = fmaxf(u, 0.f);

        // out = u @ Wf2 + bf2 : lane (q,jj) does quarter-K partial, 2 xor-reduces
        ubuf[wv][lane] = u;
        const float4* ub = (const float4*)(ubuf[wv] + q * 16);
        float p = 0.f;
#pragma unroll
        for (int kk = 0; kk < 4; ++kk) {
            float4 z = ub[kk];
            p = fmaf(z.x, W2reg[4 * kk + 0], p);
            p = fmaf(z.y, W2reg[4 * kk + 1], p);
            p = fmaf(z.z, W2reg[4 * kk + 2], p);
            p = fmaf(z.w, W2reg[4 * kk + 3], p);
        }
        p += __shfl_xor(p, 16);
        p += __shfl_xor(p, 32);
        if (lane < 16) out[(size_t)n * DOUT + jj] = p + b2v;
    }
}

// ---------------------------------------------------------------------------
extern "C" void kernel_launch(void* const* d_in, const int* in_sizes, int n_in,
                              void* d_out, int out_size, void* d_ws, size_t ws_size,
                              hipStream_t stream) {
    const float* x   = (const float*)d_in[0];
    const int*   ei  = (const int*)d_in[1];
    const float* W1  = (const float*)d_in[2];
    const float* b1  = (const float*)d_in[3];
    const float* W2  = (const float*)d_in[4];
    const float* b2  = (const float*)d_in[5];
    const float* W3  = (const float*)d_in[6];
    const float* b3  = (const float*)d_in[7];
    const float* Wf1 = (const float*)d_in[8];
    const float* bf1 = (const float*)d_in[9];
    const float* Wf2 = (const float*)d_in[10];
    const float* bf2 = (const float*)d_in[11];
    float* out = (float*)d_out;

    char* ws = (char*)d_ws;
    auto al = [](size_t v) { return (v + 255) & ~(size_t)255; };
    size_t off = 0;
    int*   cnt  = (int*)(ws + off);   off = al(off + (size_t)NN * 4);
    float* dinv = (float*)(ws + off); off = al(off + (size_t)NN * 4);
    int*   csr  = (int*)(ws + off);   off = al(off + (size_t)NN * CAP * 4);
    float* A    = (float*)(ws + off); off = al(off + (size_t)NN * DD * 4);
    float* B    = (float*)(ws + off); off = al(off + (size_t)NN * DD * 4);

    // Aliases (lifetime-disjoint): binned edges live in A (first written by
    // k_gemm_scale later); histogram/scan matrix lives in B (first written by
    // fused layer 1 later).
    int* bsrc = (int*)A;                 // EE ints = 6.4 MB
    int* bdst = (int*)A + EE;            // EE ints = 6.4 MB (A = 25.6 MB)
    int* hist = (int*)B;                 // NB*NBL ints = 154 KB

    hipMemsetAsync(cnt, 0, (size_t)NN * 4, stream);
    k_hist<<<NBL, 256, 0, stream>>>(ei, hist);
    k_scan<<<1, 256, 0, stream>>>(hist);
    k_scatter<<<NBL, 256, 0, stream>>>(ei, hist, bsrc, bdst);
    k_csr<<<NB, 256, 0, stream>>>(bsrc, bdst, hist, cnt, csr);
    k_dinv<<<(NN + 255) / 256, 256, 0, stream>>>(cnt, dinv);

    constexpr int ROWS = 16;
    int gg = (((NN + ROWS - 1) / ROWS) + 3) / 4;   // gemm grid (4 waves/block)
    int gf = (NN + 4 * NPW - 1) / (4 * NPW);       // fused grid: 3125 blocks

    // layer 1 pre-transform: hp1 = (x@W1)*dinv   (overwrites binned edges)
    k_gemm_scale<ROWS><<<gg, 256, 0, stream>>>(x, W1, dinv, A);
    // fused layer 1->2: agg(hp1)+relu+b1, then hp2 = (t@W2)*dinv
    k_fused<<<gf, 256, 0, stream>>>(A, csr, cnt, dinv, b1, W2, B);
    // fused layer 2->3
    k_fused<<<gf, 256, 0, stream>>>(B, csr, cnt, dinv, b2, W3, A);
    // fused layer 3 + FFN -> out
    k_fused_ffn<<<gf, 256, 0, stream>>>(A, csr, cnt, dinv, b3, Wf1, bf1, Wf2, bf2, out);
}

// Round 4
// 553.900 us; speedup vs baseline: 1.0575x; 1.0575x over previous
//
#include <hip/hip_runtime.h>

#define NN   100000   // nodes
#define EE   1600000  // edges
#define DD   64       // feature dim
#define DOUT 16       // output dim
#define CAP  64       // CSR slots per node (list uses 1 self + 63 edges; P(deg>63) ~ 1e-19)
#define NPW  8        // nodes per wave in fused kernels

// --- binning pipeline params ---
#define EPB  8192                      // edges per block in hist/scatter
#define NBL  ((EE + EPB - 1) / EPB)    // 196 blocks
#define BSH  9                         // bucket = dst >> 9 (512 nodes/bucket)
#define NB   196                       // ceil(100000 / 512)

// ---------------------------------------------------------------------------
// K1: per-block histogram over NB dst-buckets. hist[bucket*NBL + block].
// ---------------------------------------------------------------------------
__global__ __launch_bounds__(256) void k_hist(const int* __restrict__ ei,
                                              int* __restrict__ hist) {
    __shared__ int h[NB];
    for (int i = threadIdx.x; i < NB; i += 256) h[i] = 0;
    __syncthreads();
    int e0 = blockIdx.x * EPB;
    int e1 = min(e0 + EPB, EE);
    for (int e = e0 + (int)threadIdx.x; e < e1; e += 256) {
        int d = ei[EE + e];
        atomicAdd(&h[d >> BSH], 1);
    }
    __syncthreads();
    for (int i = threadIdx.x; i < NB; i += 256)
        hist[i * NBL + blockIdx.x] = h[i];
}

// ---------------------------------------------------------------------------
// K2: single-block exclusive scan of the NB*NBL histogram matrix (in place).
// ---------------------------------------------------------------------------
__global__ __launch_bounds__(256) void k_scan(int* __restrict__ hist) {
    const int TOT = NB * NBL;
    const int CH  = (TOT + 255) / 256;
    __shared__ int part[256];
    int t  = threadIdx.x;
    int lo = t * CH, hi = min(lo + CH, TOT);
    int s = 0;
    for (int i = lo; i < hi; ++i) s += hist[i];
    part[t] = s;
    __syncthreads();
    for (int off = 1; off < 256; off <<= 1) {   // Hillis-Steele inclusive
        int v = (t >= off) ? part[t - off] : 0;
        __syncthreads();
        part[t] += v;
        __syncthreads();
    }
    int base = (t == 0) ? 0 : part[t - 1];
    for (int i = lo; i < hi; ++i) {
        int v = hist[i];
        hist[i] = base;
        base += v;
    }
}

// ---------------------------------------------------------------------------
// K3: scatter edges into bucket-grouped int2(src,dst) array. Private ranges
// per (bucket, block) -> sequential full-line 8B writes.
// ---------------------------------------------------------------------------
__global__ __launch_bounds__(256) void k_scatter(const int* __restrict__ ei,
                                                 const int* __restrict__ hist,
                                                 int2* __restrict__ bed) {
    __shared__ int cur[NB];
    for (int i = threadIdx.x; i < NB; i += 256)
        cur[i] = hist[i * NBL + blockIdx.x];
    __syncthreads();
    int e0 = blockIdx.x * EPB;
    int e1 = min(e0 + EPB, EE);
    for (int e = e0 + (int)threadIdx.x; e < e1; e += 256) {
        int s = ei[e], d = ei[EE + e];
        int p = atomicAdd(&cur[d >> BSH], 1);
        bed[p] = make_int2(s, d);
    }
}

// ---------------------------------------------------------------------------
// K4: build padded CSR bucket-by-bucket (128 KB window per bucket, L2-hot).
// ---------------------------------------------------------------------------
__global__ __launch_bounds__(256) void k_csr(const int2* __restrict__ bed,
                                             const int* __restrict__ hist,
                                             int* __restrict__ cnt,
                                             int* __restrict__ csr) {
    int b  = blockIdx.x;
    int lo = hist[b * NBL];
    int hi = (b == NB - 1) ? EE : hist[(b + 1) * NBL];
    for (int e = lo + (int)threadIdx.x; e < hi; e += 256) {
        int2 sd = bed[e];
        int pos = atomicAdd(&cnt[sd.y], 1);
        if (pos < CAP) csr[(size_t)sd.y * CAP + pos] = sd.x;
    }
}

__global__ __launch_bounds__(256) void k_dinv(const int* __restrict__ cnt,
                                              float* __restrict__ dinv) {
    int n = blockIdx.x * 256 + threadIdx.x;
    if (n < NN) dinv[n] = rsqrtf((float)cnt[n] + 1.0f);
}

// ---------------------------------------------------------------------------
// hp[n][j] = (sum_k in[n][k] * W[k][j]) * dinv[n]   (layer-1 pre-transform)
// ---------------------------------------------------------------------------
template <int ROWS>
__global__ __launch_bounds__(256) void k_gemm_scale(const float* __restrict__ in,
                                                    const float* __restrict__ W,
                                                    const float* __restrict__ dinv,
                                                    float* __restrict__ out) {
    const int lane = threadIdx.x & 63;
    const int wv   = threadIdx.x >> 6;
    float Wreg[DD];
#pragma unroll
    for (int k = 0; k < DD; ++k) Wreg[k] = W[k * DD + lane];  // coalesced

    int base = (blockIdx.x * 4 + wv) * ROWS;
    for (int r = 0; r < ROWS; ++r) {
        int n = base + r;
        if (n >= NN) return;
        const float4* row = (const float4*)(in + (size_t)n * DD);
        float acc = 0.f;
#pragma unroll
        for (int kk = 0; kk < DD / 4; ++kk) {
            float4 q = row[kk];  // uniform address -> broadcast
            acc = fmaf(q.x, Wreg[4 * kk + 0], acc);
            acc = fmaf(q.y, Wreg[4 * kk + 1], acc);
            acc = fmaf(q.z, Wreg[4 * kk + 2], acc);
            acc = fmaf(q.w, Wreg[4 * kk + 3], acc);
        }
        out[(size_t)n * DD + lane] = acc * dinv[n];
    }
}

// ---------------------------------------------------------------------------
// Multi-row gather: lane (sub=lane>>4, m=lane&15) loads float4 = 16B of row
// list[4*batch+sub]; one dwordx4 instruction fetches 4 rows. 8 accumulators
// -> 32 rows per branchless round (covers 99.95% of nodes in ONE latency
// round). list = [n, csr slots, NN-sentinel pads]; row NN is a zero row.
// Returns aggregated float4 (features 4m..4m+3) replicated in all lanes.
// ---------------------------------------------------------------------------
__device__ __forceinline__ float4 gather_rows(const float4* __restrict__ hpv,
                                              const int* __restrict__ csr,
                                              const int* __restrict__ cnt,
                                              int n, int lane, int sub, int m) {
    int slot = csr[(size_t)n * CAP + lane];  // coalesced CSR row
    int c = cnt[n]; if (c > 63) c = 63;
    int up = __shfl_up(slot, 1);
    int list = (lane == 0) ? n : ((lane <= c) ? up : NN);
    int nbatch = (c + 4) >> 2;               // ceil((c+1)/4)

    float4 f0 = {0,0,0,0}, f1 = f0, f2 = f0, f3 = f0;
    float4 f4 = f0, f5 = f0, f6 = f0, f7 = f0;
    for (int g = 0; g < nbatch; g += 8) {
        int r0 = (g + 0 < nbatch) ? __shfl(list, 4 * (g + 0) + sub) : NN;
        int r1 = (g + 1 < nbatch) ? __shfl(list, 4 * (g + 1) + sub) : NN;
        int r2 = (g + 2 < nbatch) ? __shfl(list, 4 * (g + 2) + sub) : NN;
        int r3 = (g + 3 < nbatch) ? __shfl(list, 4 * (g + 3) + sub) : NN;
        int r4 = (g + 4 < nbatch) ? __shfl(list, 4 * (g + 4) + sub) : NN;
        int r5 = (g + 5 < nbatch) ? __shfl(list, 4 * (g + 5) + sub) : NN;
        int r6 = (g + 6 < nbatch) ? __shfl(list, 4 * (g + 6) + sub) : NN;
        int r7 = (g + 7 < nbatch) ? __shfl(list, 4 * (g + 7) + sub) : NN;
        float4 v0 = hpv[(size_t)r0 * 16 + m];
        float4 v1 = hpv[(size_t)r1 * 16 + m];
        float4 v2 = hpv[(size_t)r2 * 16 + m];
        float4 v3 = hpv[(size_t)r3 * 16 + m];
        float4 v4 = hpv[(size_t)r4 * 16 + m];
        float4 v5 = hpv[(size_t)r5 * 16 + m];
        float4 v6 = hpv[(size_t)r6 * 16 + m];
        float4 v7 = hpv[(size_t)r7 * 16 + m];
        f0.x += v0.x; f0.y += v0.y; f0.z += v0.z; f0.w += v0.w;
        f1.x += v1.x; f1.y += v1.y; f1.z += v1.z; f1.w += v1.w;
        f2.x += v2.x; f2.y += v2.y; f2.z += v2.z; f2.w += v2.w;
        f3.x += v3.x; f3.y += v3.y; f3.z += v3.z; f3.w += v3.w;
        f4.x += v4.x; f4.y += v4.y; f4.z += v4.z; f4.w += v4.w;
        f5.x += v5.x; f5.y += v5.y; f5.z += v5.z; f5.w += v5.w;
        f6.x += v6.x; f6.y += v6.y; f6.z += v6.z; f6.w += v6.w;
        f7.x += v7.x; f7.y += v7.y; f7.z += v7.z; f7.w += v7.w;
    }
    float4 s;
    s.x = ((f0.x + f1.x) + (f2.x + f3.x)) + ((f4.x + f5.x) + (f6.x + f7.x));
    s.y = ((f0.y + f1.y) + (f2.y + f3.y)) + ((f4.y + f5.y) + (f6.y + f7.y));
    s.z = ((f0.z + f1.z) + (f2.z + f3.z)) + ((f4.z + f5.z) + (f6.z + f7.z));
    s.w = ((f0.w + f1.w) + (f2.w + f3.w)) + ((f4.w + f5.w) + (f6.w + f7.w));
    // reduce across the 4 row-groups
    s.x += __shfl_xor(s.x, 16); s.y += __shfl_xor(s.y, 16);
    s.z += __shfl_xor(s.z, 16); s.w += __shfl_xor(s.w, 16);
    s.x += __shfl_xor(s.x, 32); s.y += __shfl_xor(s.y, 32);
    s.z += __shfl_xor(s.z, 32); s.w += __shfl_xor(s.w, 32);
    return s;
}

// ---------------------------------------------------------------------------
// Fused layer: t = relu(dinv[n]*agg + bias); hpn[n] = (t @ Wn) * dinv[n]
// ---------------------------------------------------------------------------
__global__ __launch_bounds__(256) void k_fused(const float* __restrict__ hp,
                                               const int* __restrict__ csr,
                                               const int* __restrict__ cnt,
                                               const float* __restrict__ dinv,
                                               const float* __restrict__ bias,
                                               const float* __restrict__ Wn,
                                               float* __restrict__ hpn) {
    __shared__ float tbuf[4][DD];
    const int lane = threadIdx.x & 63;
    const int wv   = threadIdx.x >> 6;
    const int sub  = lane >> 4;
    const int m    = lane & 15;

    float Wreg[DD];
#pragma unroll
    for (int k = 0; k < DD; ++k) Wreg[k] = Wn[k * DD + lane];
    const float4 bv4 = ((const float4*)bias)[m];
    const float4* hpv = (const float4*)hp;

    int base = (blockIdx.x * 4 + wv) * NPW;
    for (int r = 0; r < NPW; ++r) {
        int n = base + r;
        if (n >= NN) return;
        float dv = dinv[n];
        float4 s = gather_rows(hpv, csr, cnt, n, lane, sub, m);
        float4 t4;
        t4.x = fmaxf(fmaf(dv, s.x, bv4.x), 0.f);
        t4.y = fmaxf(fmaf(dv, s.y, bv4.y), 0.f);
        t4.z = fmaxf(fmaf(dv, s.z, bv4.z), 0.f);
        t4.w = fmaxf(fmaf(dv, s.w, bv4.w), 0.f);

        if (sub == 0) ((float4*)tbuf[wv])[m] = t4;  // one group writes full row
        const float4* tb = (const float4*)tbuf[wv];
        float o = 0.f;
#pragma unroll
        for (int kk = 0; kk < DD / 4; ++kk) {
            float4 q = tb[kk];  // wave-uniform -> LDS broadcast
            o = fmaf(q.x, Wreg[4 * kk + 0], o);
            o = fmaf(q.y, Wreg[4 * kk + 1], o);
            o = fmaf(q.z, Wreg[4 * kk + 2], o);
            o = fmaf(q.w, Wreg[4 * kk + 3], o);
        }
        hpn[(size_t)n * DD + lane] = o * dv;
    }
}

// ---------------------------------------------------------------------------
// Final fused layer: t3 = relu(dinv*agg+b3); u = relu(t3@Wf1+bf1);
//                    out = u@Wf2 + bf2.
// ---------------------------------------------------------------------------
__global__ __launch_bounds__(256) void k_fused_ffn(const float* __restrict__ hp,
                                                   const int* __restrict__ csr,
                                                   const int* __restrict__ cnt,
                                                   const float* __restrict__ dinv,
                                                   const float* __restrict__ b3,
                                                   const float* __restrict__ Wf1,
                                                   const float* __restrict__ bf1,
                                                   const float* __restrict__ Wf2,
                                                   const float* __restrict__ bf2,
                                                   float* __restrict__ out) {
    __shared__ float tbuf[4][DD];
    __shared__ float ubuf[4][DD];
    const int lane = threadIdx.x & 63;
    const int wv   = threadIdx.x >> 6;
    const int sub  = lane >> 4;   // also the quarter for the 2nd matmul
    const int m    = lane & 15;

    float W1reg[DD];
#pragma unroll
    for (int k = 0; k < DD; ++k) W1reg[k] = Wf1[k * DD + lane];
    float W2reg[16];
#pragma unroll
    for (int kk = 0; kk < 16; ++kk) W2reg[kk] = Wf2[(sub * 16 + kk) * DOUT + m];
    const float4 b3v4 = ((const float4*)b3)[m];
    const float  b1v  = bf1[lane];
    const float  b2v  = bf2[m];
    const float4* hpv = (const float4*)hp;

    int base = (blockIdx.x * 4 + wv) * NPW;
    for (int r = 0; r < NPW; ++r) {
        int n = base + r;
        if (n >= NN) return;
        float dv = dinv[n];
        float4 s = gather_rows(hpv, csr, cnt, n, lane, sub, m);
        float4 t4;
        t4.x = fmaxf(fmaf(dv, s.x, b3v4.x), 0.f);
        t4.y = fmaxf(fmaf(dv, s.y, b3v4.y), 0.f);
        t4.z = fmaxf(fmaf(dv, s.z, b3v4.z), 0.f);
        t4.w = fmaxf(fmaf(dv, s.w, b3v4.w), 0.f);

        if (sub == 0) ((float4*)tbuf[wv])[m] = t4;
        const float4* tb = (const float4*)tbuf[wv];
        float u = b1v;
#pragma unroll
        for (int kk = 0; kk < DD / 4; ++kk) {
            float4 qd = tb[kk];
            u = fmaf(qd.x, W1reg[4 * kk + 0], u);
            u = fmaf(qd.y, W1reg[4 * kk + 1], u);
            u = fmaf(qd.z, W1reg[4 * kk + 2], u);
            u = fmaf(qd.w, W1reg[4 * kk + 3], u);
        }
        u = fmaxf(u, 0.f);

        // out = u @ Wf2 + bf2 : lane (sub,m) does quarter-K partial, 2 xor-reduces
        ubuf[wv][lane] = u;
        const float4* ub = (const float4*)(ubuf[wv] + sub * 16);
        float p = 0.f;
#pragma unroll
        for (int kk = 0; kk < 4; ++kk) {
            float4 z = ub[kk];
            p = fmaf(z.x, W2reg[4 * kk + 0], p);
            p = fmaf(z.y, W2reg[4 * kk + 1], p);
            p = fmaf(z.z, W2reg[4 * kk + 2], p);
            p = fmaf(z.w, W2reg[4 * kk + 3], p);
        }
        p += __shfl_xor(p, 16);
        p += __shfl_xor(p, 32);
        if (lane < 16) out[(size_t)n * DOUT + m] = p + b2v;
    }
}

// ---------------------------------------------------------------------------
extern "C" void kernel_launch(void* const* d_in, const int* in_sizes, int n_in,
                              void* d_out, int out_size, void* d_ws, size_t ws_size,
                              hipStream_t stream) {
    const float* x   = (const float*)d_in[0];
    const int*   ei  = (const int*)d_in[1];
    const float* W1  = (const float*)d_in[2];
    const float* b1  = (const float*)d_in[3];
    const float* W2  = (const float*)d_in[4];
    const float* b2  = (const float*)d_in[5];
    const float* W3  = (const float*)d_in[6];
    const float* b3  = (const float*)d_in[7];
    const float* Wf1 = (const float*)d_in[8];
    const float* bf1 = (const float*)d_in[9];
    const float* Wf2 = (const float*)d_in[10];
    const float* bf2 = (const float*)d_in[11];
    float* out = (float*)d_out;

    char* ws = (char*)d_ws;
    auto al = [](size_t v) { return (v + 255) & ~(size_t)255; };
    size_t off = 0;
    int*   cnt  = (int*)(ws + off);   off = al(off + (size_t)NN * 4);
    float* dinv = (float*)(ws + off); off = al(off + (size_t)NN * 4);
    int*   csr  = (int*)(ws + off);   off = al(off + (size_t)NN * CAP * 4);
    float* A    = (float*)(ws + off); off = al(off + (size_t)(NN + 1) * DD * 4);
    float* B    = (float*)(ws + off); off = al(off + (size_t)(NN + 1) * DD * 4);

    // Lifetime-disjoint aliases: binned int2 edges in A's first 12.8 MB
    // (A rows overwritten by k_gemm_scale later; A's zero row at 25.6 MB is
    // beyond the alias); hist matrix in B's first 154 KB.
    int2* bed  = (int2*)A;
    int*  hist = (int*)B;

    hipMemsetAsync(cnt, 0, (size_t)NN * 4, stream);
    hipMemsetAsync(A + (size_t)NN * DD, 0, DD * 4, stream);  // sentinel zero row
    hipMemsetAsync(B + (size_t)NN * DD, 0, DD * 4, stream);

    k_hist<<<NBL, 256, 0, stream>>>(ei, hist);
    k_scan<<<1, 256, 0, stream>>>(hist);
    k_scatter<<<NBL, 256, 0, stream>>>(ei, hist, bed);
    k_csr<<<NB, 256, 0, stream>>>(bed, hist, cnt, csr);
    k_dinv<<<(NN + 255) / 256, 256, 0, stream>>>(cnt, dinv);

    constexpr int ROWS = 16;
    int gg = (((NN + ROWS - 1) / ROWS) + 3) / 4;   // gemm grid (4 waves/block)
    int gf = (NN + 4 * NPW - 1) / (4 * NPW);       // fused grid: 3125 blocks

    // layer 1 pre-transform: hp1 = (x@W1)*dinv   (overwrites binned edges)
    k_gemm_scale<ROWS><<<gg, 256, 0, stream>>>(x, W1, dinv, A);
    // fused layer 1->2: agg(hp1)+relu+b1, then hp2 = (t@W2)*dinv
    k_fused<<<gf, 256, 0, stream>>>(A, csr, cnt, dinv, b1, W2, B);
    // fused layer 2->3
    k_fused<<<gf, 256, 0, stream>>>(B, csr, cnt, dinv, b2, W3, A);
    // fused layer 3 + FFN -> out
    k_fused_ffn<<<gf, 256, 0, stream>>>(A, csr, cnt, dinv, b3, Wf1, bf1, Wf2, bf2, out);
}

// Round 5
// 497.665 us; speedup vs baseline: 1.1770x; 1.1130x over previous
//
#include <hip/hip_runtime.h>

#define NN   100000   // nodes
#define EE   1600000  // edges
#define DD   64       // feature dim
#define DOUT 16       // output dim
#define CAP  64       // CSR slots per node (list uses 1 self + 63 edges)
#define NPW  8        // nodes per wave in fused kernels

// --- binning pipeline params ---
#define EPB  8192                      // edges per block in hist/scatter
#define NBL  ((EE + EPB - 1) / EPB)    // 196 blocks
#define BSH  9                         // bucket = dst >> 9 (512 nodes/bucket)
#define NB   196                       // ceil(100000 / 512)

// ---------------------------------------------------------------------------
// K1: per-block histogram over NB dst-buckets. hist[bucket*NBL + block].
// ---------------------------------------------------------------------------
__global__ __launch_bounds__(256) void k_hist(const int* __restrict__ ei,
                                              int* __restrict__ hist) {
    __shared__ int h[NB];
    for (int i = threadIdx.x; i < NB; i += 256) h[i] = 0;
    __syncthreads();
    int e0 = blockIdx.x * EPB;
    int e1 = min(e0 + EPB, EE);
    for (int e = e0 + (int)threadIdx.x; e < e1; e += 256) {
        int d = ei[EE + e];
        atomicAdd(&h[d >> BSH], 1);
    }
    __syncthreads();
    for (int i = threadIdx.x; i < NB; i += 256)
        hist[i * NBL + blockIdx.x] = h[i];
}

// ---------------------------------------------------------------------------
// K2: single-block exclusive scan of the NB*NBL histogram matrix (in place).
// ---------------------------------------------------------------------------
__global__ __launch_bounds__(256) void k_scan(int* __restrict__ hist) {
    const int TOT = NB * NBL;
    const int CH  = (TOT + 255) / 256;
    __shared__ int part[256];
    int t  = threadIdx.x;
    int lo = t * CH, hi = min(lo + CH, TOT);
    int s = 0;
    for (int i = lo; i < hi; ++i) s += hist[i];
    part[t] = s;
    __syncthreads();
    for (int off = 1; off < 256; off <<= 1) {   // Hillis-Steele inclusive
        int v = (t >= off) ? part[t - off] : 0;
        __syncthreads();
        part[t] += v;
        __syncthreads();
    }
    int base = (t == 0) ? 0 : part[t - 1];
    for (int i = lo; i < hi; ++i) {
        int v = hist[i];
        hist[i] = base;
        base += v;
    }
}

// ---------------------------------------------------------------------------
// K3: scatter edges into bucket-grouped int2(src,dst) array. Private ranges
// per (bucket, block) -> sequential full-line 8B writes.
// ---------------------------------------------------------------------------
__global__ __launch_bounds__(256) void k_scatter(const int* __restrict__ ei,
                                                 const int* __restrict__ hist,
                                                 int2* __restrict__ bed) {
    __shared__ int cur[NB];
    for (int i = threadIdx.x; i < NB; i += 256)
        cur[i] = hist[i * NBL + blockIdx.x];
    __syncthreads();
    int e0 = blockIdx.x * EPB;
    int e1 = min(e0 + EPB, EE);
    for (int e = e0 + (int)threadIdx.x; e < e1; e += 256) {
        int s = ei[e], d = ei[EE + e];
        int p = atomicAdd(&cur[d >> BSH], 1);
        bed[p] = make_int2(s, d);
    }
}

// ---------------------------------------------------------------------------
// K4: build padded CSR bucket-by-bucket (128 KB window per bucket, L2-hot).
// ---------------------------------------------------------------------------
__global__ __launch_bounds__(256) void k_csr(const int2* __restrict__ bed,
                                             const int* __restrict__ hist,
                                             int* __restrict__ cnt,
                                             int* __restrict__ csr) {
    int b  = blockIdx.x;
    int lo = hist[b * NBL];
    int hi = (b == NB - 1) ? EE : hist[(b + 1) * NBL];
    for (int e = lo + (int)threadIdx.x; e < hi; e += 256) {
        int2 sd = bed[e];
        int pos = atomicAdd(&cnt[sd.y], 1);
        if (pos < CAP) csr[(size_t)sd.y * CAP + pos] = sd.x;
    }
}

__global__ __launch_bounds__(256) void k_dinv(const int* __restrict__ cnt,
                                              float* __restrict__ dinv) {
    int n = blockIdx.x * 256 + threadIdx.x;
    if (n < NN) dinv[n] = rsqrtf((float)cnt[n] + 1.0f);
}

// ---------------------------------------------------------------------------
// hp[n][j] = (sum_k in[n][k] * W[k][j]) * dinv[n]   (layer-1 pre-transform)
// ---------------------------------------------------------------------------
template <int ROWS>
__global__ __launch_bounds__(256) void k_gemm_scale(const float* __restrict__ in,
                                                    const float* __restrict__ W,
                                                    const float* __restrict__ dinv,
                                                    float* __restrict__ out) {
    const int lane = threadIdx.x & 63;
    const int wv   = threadIdx.x >> 6;
    float Wreg[DD];
#pragma unroll
    for (int k = 0; k < DD; ++k) Wreg[k] = W[k * DD + lane];  // coalesced

    int base = (blockIdx.x * 4 + wv) * ROWS;
    for (int r = 0; r < ROWS; ++r) {
        int n = base + r;
        if (n >= NN) return;
        const float4* row = (const float4*)(in + (size_t)n * DD);
        float acc = 0.f;
#pragma unroll
        for (int kk = 0; kk < DD / 4; ++kk) {
            float4 q = row[kk];  // uniform address -> broadcast
            acc = fmaf(q.x, Wreg[4 * kk + 0], acc);
            acc = fmaf(q.y, Wreg[4 * kk + 1], acc);
            acc = fmaf(q.z, Wreg[4 * kk + 2], acc);
            acc = fmaf(q.w, Wreg[4 * kk + 3], acc);
        }
        out[(size_t)n * DD + lane] = acc * dinv[n];
    }
}

// ---------------------------------------------------------------------------
// Multi-row gather: lane (sub=lane>>4, m=lane&15) loads float4 = 16B of row
// list[4*batch+sub]; one dwordx4 fetches 4 rows; 8 loads in flight cover 32
// rows (>=99.9% of nodes) in ONE latency round. Only TWO float4 accumulators
// (loads folded in arrival order; compiler waits vmcnt(7..0) incrementally)
// to stay under the 64-VGPR occupancy cliff. list = [n, csr slots, NN pads];
// row NN is a zero sentinel. Returns sum over features 4m..4m+3, all lanes.
// ---------------------------------------------------------------------------
__device__ __forceinline__ float4 gather_rows(const float4* __restrict__ hpv,
                                              const int* __restrict__ csr,
                                              const int* __restrict__ cnt,
                                              int n, int lane, int sub, int m) {
    int slot = csr[(size_t)n * CAP + lane];  // coalesced CSR row
    int c = cnt[n]; if (c > 63) c = 63;
    int up = __shfl_up(slot, 1);
    int list = (lane == 0) ? n : ((lane <= c) ? up : NN);
    int nbatch = (c + 4) >> 2;               // ceil((c+1)/4)

    float4 fa = {0, 0, 0, 0}, fb = fa;
    for (int g = 0; g < nbatch; g += 8) {
        int r0 = (g + 0 < nbatch) ? __shfl(list, 4 * (g + 0) + sub) : NN;
        int r1 = (g + 1 < nbatch) ? __shfl(list, 4 * (g + 1) + sub) : NN;
        int r2 = (g + 2 < nbatch) ? __shfl(list, 4 * (g + 2) + sub) : NN;
        int r3 = (g + 3 < nbatch) ? __shfl(list, 4 * (g + 3) + sub) : NN;
        int r4 = (g + 4 < nbatch) ? __shfl(list, 4 * (g + 4) + sub) : NN;
        int r5 = (g + 5 < nbatch) ? __shfl(list, 4 * (g + 5) + sub) : NN;
        int r6 = (g + 6 < nbatch) ? __shfl(list, 4 * (g + 6) + sub) : NN;
        int r7 = (g + 7 < nbatch) ? __shfl(list, 4 * (g + 7) + sub) : NN;
        float4 v0 = hpv[(size_t)r0 * 16 + m];
        float4 v1 = hpv[(size_t)r1 * 16 + m];
        float4 v2 = hpv[(size_t)r2 * 16 + m];
        float4 v3 = hpv[(size_t)r3 * 16 + m];
        float4 v4 = hpv[(size_t)r4 * 16 + m];
        float4 v5 = hpv[(size_t)r5 * 16 + m];
        float4 v6 = hpv[(size_t)r6 * 16 + m];
        float4 v7 = hpv[(size_t)r7 * 16 + m];
        fa.x += v0.x; fa.y += v0.y; fa.z += v0.z; fa.w += v0.w;
        fb.x += v1.x; fb.y += v1.y; fb.z += v1.z; fb.w += v1.w;
        fa.x += v2.x; fa.y += v2.y; fa.z += v2.z; fa.w += v2.w;
        fb.x += v3.x; fb.y += v3.y; fb.z += v3.z; fb.w += v3.w;
        fa.x += v4.x; fa.y += v4.y; fa.z += v4.z; fa.w += v4.w;
        fb.x += v5.x; fb.y += v5.y; fb.z += v5.z; fb.w += v5.w;
        fa.x += v6.x; fa.y += v6.y; fa.z += v6.z; fa.w += v6.w;
        fb.x += v7.x; fb.y += v7.y; fb.z += v7.z; fb.w += v7.w;
    }
    float4 s;
    s.x = fa.x + fb.x; s.y = fa.y + fb.y; s.z = fa.z + fb.z; s.w = fa.w + fb.w;
    s.x += __shfl_xor(s.x, 16); s.y += __shfl_xor(s.y, 16);
    s.z += __shfl_xor(s.z, 16); s.w += __shfl_xor(s.w, 16);
    s.x += __shfl_xor(s.x, 32); s.y += __shfl_xor(s.y, 32);
    s.z += __shfl_xor(s.z, 32); s.w += __shfl_xor(s.w, 32);
    return s;
}

// ---------------------------------------------------------------------------
// Fused layer: t = relu(dinv[n]*agg + bias); hpn[n] = (t @ Wn) * dinv[n]
// Wn lives in LDS (16 KB): matmul reads sW[k*64+lane] (stride-1 across lanes
// = 2-way bank aliasing = free; single base vaddr + immediate offsets).
// ---------------------------------------------------------------------------
__global__ __launch_bounds__(256, 8) void k_fused(const float* __restrict__ hp,
                                                  const int* __restrict__ csr,
                                                  const int* __restrict__ cnt,
                                                  const float* __restrict__ dinv,
                                                  const float* __restrict__ bias,
                                                  const float* __restrict__ Wn,
                                                  float* __restrict__ hpn) {
    __shared__ float sW[DD * DD];
    __shared__ float tbuf[4][DD];
    const int lane = threadIdx.x & 63;
    const int wv   = threadIdx.x >> 6;
    const int sub  = lane >> 4;
    const int m    = lane & 15;

    for (int i = threadIdx.x; i < DD * DD / 4; i += 256)
        ((float4*)sW)[i] = ((const float4*)Wn)[i];  // L2-broadcast staging
    __syncthreads();

    const float4 bv4 = ((const float4*)bias)[m];
    const float4* hpv = (const float4*)hp;
    const float* wcol = &sW[lane];

    int base = (blockIdx.x * 4 + wv) * NPW;
    for (int r = 0; r < NPW; ++r) {
        int n = base + r;
        if (n >= NN) return;
        float dv = dinv[n];
        float4 s = gather_rows(hpv, csr, cnt, n, lane, sub, m);
        float4 t4;
        t4.x = fmaxf(fmaf(dv, s.x, bv4.x), 0.f);
        t4.y = fmaxf(fmaf(dv, s.y, bv4.y), 0.f);
        t4.z = fmaxf(fmaf(dv, s.z, bv4.z), 0.f);
        t4.w = fmaxf(fmaf(dv, s.w, bv4.w), 0.f);

        if (sub == 0) ((float4*)tbuf[wv])[m] = t4;  // wave-private slot
        const float4* tb = (const float4*)tbuf[wv];
        float o = 0.f;
#pragma unroll
        for (int kk = 0; kk < DD / 4; ++kk) {
            float4 q = tb[kk];  // wave-uniform -> LDS broadcast
            o = fmaf(q.x, wcol[(4 * kk + 0) * DD], o);
            o = fmaf(q.y, wcol[(4 * kk + 1) * DD], o);
            o = fmaf(q.z, wcol[(4 * kk + 2) * DD], o);
            o = fmaf(q.w, wcol[(4 * kk + 3) * DD], o);
        }
        hpn[(size_t)n * DD + lane] = o * dv;
    }
}

// ---------------------------------------------------------------------------
// Final fused layer: t3 = relu(dinv*agg+b3); u = relu(t3@Wf1+bf1);
//                    out = u@Wf2 + bf2.   Wf1 (16 KB) and Wf2 (4 KB) in LDS.
// ---------------------------------------------------------------------------
__global__ __launch_bounds__(256, 8) void k_fused_ffn(const float* __restrict__ hp,
                                                      const int* __restrict__ csr,
                                                      const int* __restrict__ cnt,
                                                      const float* __restrict__ dinv,
                                                      const float* __restrict__ b3,
                                                      const float* __restrict__ Wf1,
                                                      const float* __restrict__ bf1,
                                                      const float* __restrict__ Wf2,
                                                      const float* __restrict__ bf2,
                                                      float* __restrict__ out) {
    __shared__ float sW1[DD * DD];
    __shared__ float sW2[DD * DOUT];
    __shared__ float tbuf[4][DD];
    __shared__ float ubuf[4][DD];
    const int lane = threadIdx.x & 63;
    const int wv   = threadIdx.x >> 6;
    const int sub  = lane >> 4;   // also the K-quarter for the 2nd matmul
    const int m    = lane & 15;

    for (int i = threadIdx.x; i < DD * DD / 4; i += 256)
        ((float4*)sW1)[i] = ((const float4*)Wf1)[i];
    for (int i = threadIdx.x; i < DD * DOUT / 4; i += 256)
        ((float4*)sW2)[i] = ((const float4*)Wf2)[i];
    __syncthreads();

    const float4 b3v4 = ((const float4*)b3)[m];
    const float  b1v  = bf1[lane];
    const float  b2v  = bf2[m];
    const float4* hpv = (const float4*)hp;
    const float* w1col = &sW1[lane];
    const float* w2p   = &sW2[sub * 16 * DOUT + m];  // (sub*16+kk)*16 + m

    int base = (blockIdx.x * 4 + wv) * NPW;
    for (int r = 0; r < NPW; ++r) {
        int n = base + r;
        if (n >= NN) return;
        float dv = dinv[n];
        float4 s = gather_rows(hpv, csr, cnt, n, lane, sub, m);
        float4 t4;
        t4.x = fmaxf(fmaf(dv, s.x, b3v4.x), 0.f);
        t4.y = fmaxf(fmaf(dv, s.y, b3v4.y), 0.f);
        t4.z = fmaxf(fmaf(dv, s.z, b3v4.z), 0.f);
        t4.w = fmaxf(fmaf(dv, s.w, b3v4.w), 0.f);

        if (sub == 0) ((float4*)tbuf[wv])[m] = t4;
        const float4* tb = (const float4*)tbuf[wv];
        float u = b1v;
#pragma unroll
        for (int kk = 0; kk < DD / 4; ++kk) {
            float4 qd = tb[kk];
            u = fmaf(qd.x, w1col[(4 * kk + 0) * DD], u);
            u = fmaf(qd.y, w1col[(4 * kk + 1) * DD], u);
            u = fmaf(qd.z, w1col[(4 * kk + 2) * DD], u);
            u = fmaf(qd.w, w1col[(4 * kk + 3) * DD], u);
        }
        u = fmaxf(u, 0.f);

        // out = u @ Wf2 + bf2 : lane (sub,m) does quarter-K partial, 2 xor-reduces
        ubuf[wv][lane] = u;
        const float4* ub = (const float4*)(ubuf[wv] + sub * 16);
        float p = 0.f;
#pragma unroll
        for (int kk = 0; kk < 4; ++kk) {
            float4 z = ub[kk];
            p = fmaf(z.x, w2p[(4 * kk + 0) * DOUT], p);
            p = fmaf(z.y, w2p[(4 * kk + 1) * DOUT], p);
            p = fmaf(z.z, w2p[(4 * kk + 2) * DOUT], p);
            p = fmaf(z.w, w2p[(4 * kk + 3) * DOUT], p);
        }
        p += __shfl_xor(p, 16);
        p += __shfl_xor(p, 32);
        if (lane < 16) out[(size_t)n * DOUT + m] = p + b2v;
    }
}

// ---------------------------------------------------------------------------
extern "C" void kernel_launch(void* const* d_in, const int* in_sizes, int n_in,
                              void* d_out, int out_size, void* d_ws, size_t ws_size,
                              hipStream_t stream) {
    const float* x   = (const float*)d_in[0];
    const int*   ei  = (const int*)d_in[1];
    const float* W1  = (const float*)d_in[2];
    const float* b1  = (const float*)d_in[3];
    const float* W2  = (const float*)d_in[4];
    const float* b2  = (const float*)d_in[5];
    const float* W3  = (const float*)d_in[6];
    const float* b3  = (const float*)d_in[7];
    const float* Wf1 = (const float*)d_in[8];
    const float* bf1 = (const float*)d_in[9];
    const float* Wf2 = (const float*)d_in[10];
    const float* bf2 = (const float*)d_in[11];
    float* out = (float*)d_out;

    char* ws = (char*)d_ws;
    auto al = [](size_t v) { return (v + 255) & ~(size_t)255; };
    size_t off = 0;
    int*   cnt  = (int*)(ws + off);   off = al(off + (size_t)NN * 4);
    float* dinv = (float*)(ws + off); off = al(off + (size_t)NN * 4);
    int*   csr  = (int*)(ws + off);   off = al(off + (size_t)NN * CAP * 4);
    float* A    = (float*)(ws + off); off = al(off + (size_t)(NN + 1) * DD * 4);
    float* B    = (float*)(ws + off); off = al(off + (size_t)(NN + 1) * DD * 4);

    // Lifetime-disjoint aliases: binned int2 edges in A's first 12.8 MB
    // (overwritten later by k_gemm_scale); hist matrix in B's first 154 KB.
    int2* bed  = (int2*)A;
    int*  hist = (int*)B;

    hipMemsetAsync(cnt, 0, (size_t)NN * 4, stream);
    hipMemsetAsync(A + (size_t)NN * DD, 0, DD * 4, stream);  // sentinel zero row
    hipMemsetAsync(B + (size_t)NN * DD, 0, DD * 4, stream);

    k_hist<<<NBL, 256, 0, stream>>>(ei, hist);
    k_scan<<<1, 256, 0, stream>>>(hist);
    k_scatter<<<NBL, 256, 0, stream>>>(ei, hist, bed);
    k_csr<<<NB, 256, 0, stream>>>(bed, hist, cnt, csr);
    k_dinv<<<(NN + 255) / 256, 256, 0, stream>>>(cnt, dinv);

    constexpr int ROWS = 16;
    int gg = (((NN + ROWS - 1) / ROWS) + 3) / 4;   // gemm grid (4 waves/block)
    int gf = (NN + 4 * NPW - 1) / (4 * NPW);       // fused grid: 3125 blocks

    // layer 1 pre-transform: hp1 = (x@W1)*dinv   (overwrites binned edges)
    k_gemm_scale<ROWS><<<gg, 256, 0, stream>>>(x, W1, dinv, A);
    // fused layer 1->2: agg(hp1)+relu+b1, then hp2 = (t@W2)*dinv
    k_fused<<<gf, 256, 0, stream>>>(A, csr, cnt, dinv, b1, W2, B);
    // fused layer 2->3
    k_fused<<<gf, 256, 0, stream>>>(B, csr, cnt, dinv, b2, W3, A);
    // fused layer 3 + FFN -> out
    k_fused_ffn<<<gf, 256, 0, stream>>>(A, csr, cnt, dinv, b3, Wf1, bf1, Wf2, bf2, out);
}